// Round 2
// baseline (329.987 us; speedup 1.0000x reference)
//
#include <hip/hip_runtime.h>

// Y = X @ H, H = normalized 4096x4096 Sylvester-Hadamard (symmetric).
// = per-row FWHT * 2^-6. Memory-bound: 256 MB traffic -> ~41 us at 6.3 TB/s.
//
// This version: one WAVE per row, zero barriers, zero LDS storage.
// Element index i (12 bits) split as i = 256*j + 4*lane + r:
//   bits 0..1  (r)    : in-register butterflies inside each float4
//   bits 2..7  (lane) : 6 x __shfl_xor (ds_bpermute) butterfly stages
//   bits 8..11 (j)    : in-register butterflies across the 16 float4s
// FWHT stages commute, so this ordering is valid.

#define N12 4096
#define TPB 256   // 4 independent waves per block, one row each

__global__ __launch_bounds__(TPB, 5) void fwht4096_wave(const float* __restrict__ X,
                                                        float* __restrict__ Y) {
    const int lane = threadIdx.x & 63;
    const int wave = threadIdx.x >> 6;
    const long long row = (long long)blockIdx.x * 4 + wave;

    const float4* __restrict__ x4 = (const float4*)(X + row * N12);
    float4*       __restrict__ y4 = (float4*)(Y + row * N12);

    float4 q[16];

    // Coalesced loads: per j, the wave reads 1 KB contiguous (64 x dwordx4).
#pragma unroll
    for (int j = 0; j < 16; ++j) q[j] = x4[(j << 6) + lane];

    // ---- bits 0,1: radix-4 butterfly inside each float4 (strides 1,2)
#pragma unroll
    for (int j = 0; j < 16; ++j) {
        float4 f = q[j];
        float s0 = f.x + f.y, d0 = f.x - f.y;
        float s1 = f.z + f.w, d1 = f.z - f.w;
        q[j].x = s0 + s1;  q[j].y = d0 + d1;
        q[j].z = s0 - s1;  q[j].w = d0 - d1;
    }

    // ---- bits 2..7: cross-lane butterflies, element strides 4..128.
    // new = partner + sgn*mine  (sgn = +1 on low lane, -1 on high lane)
#pragma unroll
    for (int m = 1; m <= 32; m <<= 1) {
        const float sgn = (lane & m) ? -1.0f : 1.0f;
#pragma unroll
        for (int j = 0; j < 16; ++j) {
            float4 f = q[j];
            float px = __shfl_xor(f.x, m, 64);
            float py = __shfl_xor(f.y, m, 64);
            float pz = __shfl_xor(f.z, m, 64);
            float pw = __shfl_xor(f.w, m, 64);
            q[j].x = fmaf(sgn, f.x, px);
            q[j].y = fmaf(sgn, f.y, py);
            q[j].z = fmaf(sgn, f.z, pz);
            q[j].w = fmaf(sgn, f.w, pw);
        }
    }

    // ---- bits 8..11: register butterflies across j (strides 256..2048)
#pragma unroll
    for (int d = 1; d < 16; d <<= 1) {
#pragma unroll
        for (int j = 0; j < 16; ++j) {
            if ((j & d) == 0) {
                float4 u = q[j], w = q[j + d];
                q[j].x = u.x + w.x;  q[j + d].x = u.x - w.x;
                q[j].y = u.y + w.y;  q[j + d].y = u.y - w.y;
                q[j].z = u.z + w.z;  q[j + d].z = u.z - w.z;
                q[j].w = u.w + w.w;  q[j + d].w = u.w - w.w;
            }
        }
    }

    // ---- scaled coalesced stores (2^-6 normalization)
    const float s = 0.015625f;
#pragma unroll
    for (int j = 0; j < 16; ++j) {
        float4 f = q[j];
        f.x *= s; f.y *= s; f.z *= s; f.w *= s;
        y4[(j << 6) + lane] = f;
    }
}

extern "C" void kernel_launch(void* const* d_in, const int* in_sizes, int n_in,
                              void* d_out, int out_size, void* d_ws, size_t ws_size,
                              hipStream_t stream) {
    const float* X = (const float*)d_in[0];   // (ROWS, 4096) fp32
    // d_in[1] (dense H) unused: FWHT computed directly.
    float* Y = (float*)d_out;
    const int rows = in_sizes[0] / N12;       // 8192
    hipLaunchKernelGGL(fwht4096_wave, dim3(rows / 4), dim3(TPB), 0, stream, X, Y);
}

// Round 3
// 253.097 us; speedup vs baseline: 1.3038x; 1.3038x over previous
//
#include <hip/hip_runtime.h>

// Y = X @ H, H = normalized 4096x4096 Sylvester-Hadamard (symmetric).
// = per-row FWHT * 2^-6. Memory-bound: ~256 MB traffic -> ~41 us at 6.3 TB/s.
//
// Lesson from R1/R2: hipcc does NOT scalar-promote per-thread arrays here
// (R1: VGPR=20 for a 16-float working set; R2: VGPR=48 for 64 floats, with
// ~330 MB of scratch HBM traffic). This version uses 16 NAMED scalar
// registers and fully hand-unrolled butterflies -- no arrays anywhere.
//
// Structure: one 256-thread block per row, 16 elements/thread.
//   Phase A: i = 16*t + k      -> butterflies on k   (global strides 1..8)
//   Phase B: i = a + 16*b + 256*c (t = a + 16*c) -> butterflies on b (16..128)
//   Phase C: i = a + 16*b2 + 256*cc (t = a + 16*b2) -> butterflies on cc (256..2048)
// LDS padded addr(i) = i + (i>>4): all exchange patterns <=3-way banked.

#define N12 4096
#define TPB 256

#define BF(p, q) do { float _u = (p), _w = (q); (p) = _u + _w; (q) = _u - _w; } while (0)

// 4 butterfly stages (local strides 1,2,4,8) over the 16 named scalars.
#define BFLY16()  do { \
    BF(v0,v1);  BF(v2,v3);  BF(v4,v5);   BF(v6,v7);   BF(v8,v9);  BF(v10,v11); BF(v12,v13); BF(v14,v15); \
    BF(v0,v2);  BF(v1,v3);  BF(v4,v6);   BF(v5,v7);   BF(v8,v10); BF(v9,v11);  BF(v12,v14); BF(v13,v15); \
    BF(v0,v4);  BF(v1,v5);  BF(v2,v6);   BF(v3,v7);   BF(v8,v12); BF(v9,v13);  BF(v10,v14); BF(v11,v15); \
    BF(v0,v8);  BF(v1,v9);  BF(v2,v10);  BF(v3,v11);  BF(v4,v12); BF(v5,v13);  BF(v6,v14);  BF(v7,v15); \
} while (0)

__global__ __launch_bounds__(TPB) void fwht4096_reg(const float* __restrict__ X,
                                                    float* __restrict__ Y) {
    __shared__ float lds[N12 + (N12 >> 4)];  // 4352 floats = 17 KB

    const int t = threadIdx.x;
    const long long row = blockIdx.x;
    const float* __restrict__ x = X + row * N12;
    float*       __restrict__ y = Y + row * N12;

    float v0, v1, v2, v3, v4, v5, v6, v7, v8, v9, v10, v11, v12, v13, v14, v15;

    // ---- Phase A load: thread t holds i = 16*t + k, as 4 float4 loads.
    const float4* __restrict__ x4 = (const float4*)x + (t << 2);
    {
        float4 f0 = x4[0], f1 = x4[1], f2 = x4[2], f3 = x4[3];
        v0  = f0.x; v1  = f0.y; v2  = f0.z; v3  = f0.w;
        v4  = f1.x; v5  = f1.y; v6  = f1.z; v7  = f1.w;
        v8  = f2.x; v9  = f2.y; v10 = f2.z; v11 = f2.w;
        v12 = f3.x; v13 = f3.y; v14 = f3.z; v15 = f3.w;
    }
    BFLY16();  // global strides 1,2,4,8

    // ---- Exchange A->B: write addr = 17*t + k (17t mod 32 bijective -> 2-way, free)
    {
        float* w = lds + 17 * t;
        w[0]=v0;  w[1]=v1;  w[2]=v2;   w[3]=v3;   w[4]=v4;   w[5]=v5;   w[6]=v6;   w[7]=v7;
        w[8]=v8;  w[9]=v9;  w[10]=v10; w[11]=v11; w[12]=v12; w[13]=v13; w[14]=v14; w[15]=v15;
    }
    __syncthreads();

    // ---- Phase B: t = a + 16*c holds i = a + 16*b + 256*c; addr = a + 17*b + 272*c
    const int a = t & 15;
    const int c = t >> 4;
    {
        const float* r = lds + a + 272 * c;
        v0 = r[0];    v1 = r[17];   v2  = r[34];  v3  = r[51];
        v4 = r[68];   v5 = r[85];   v6  = r[102]; v7  = r[119];
        v8 = r[136];  v9 = r[153];  v10 = r[170]; v11 = r[187];
        v12 = r[204]; v13 = r[221]; v14 = r[238]; v15 = r[255];
    }
    BFLY16();  // global strides 16,32,64,128

    // ---- Exchange B->C: each thread overwrites exactly the addresses it read
    // (disjoint per-thread sets) -> no barrier before the writes.
    {
        float* w = lds + a + 272 * c;
        w[0]=v0;    w[17]=v1;   w[34]=v2;   w[51]=v3;
        w[68]=v4;   w[85]=v5;   w[102]=v6;  w[119]=v7;
        w[136]=v8;  w[153]=v9;  w[170]=v10; w[187]=v11;
        w[204]=v12; w[221]=v13; w[238]=v14; w[255]=v15;
    }
    __syncthreads();

    // ---- Phase C: t = a + 16*b2 holds i = a + 16*b2 + 256*cc; addr = a + 17*b2 + 272*cc
    {
        const float* r = lds + a + 17 * (t >> 4);
        v0 = r[0];      v1 = r[272];    v2  = r[544];   v3  = r[816];
        v4 = r[1088];   v5 = r[1360];   v6  = r[1632];  v7  = r[1904];
        v8 = r[2176];   v9 = r[2448];   v10 = r[2720];  v11 = r[2992];
        v12 = r[3264];  v13 = r[3536];  v14 = r[3808];  v15 = r[4080];
    }
    BFLY16();  // global strides 256,512,1024,2048

    // ---- Store: y[t + 256*cc] -> each wave store = 256 B contiguous segment
    const float s = 0.015625f;  // 2^-6
    y[t]        = v0  * s;  y[t + 256]  = v1  * s;  y[t + 512]  = v2  * s;  y[t + 768]  = v3  * s;
    y[t + 1024] = v4  * s;  y[t + 1280] = v5  * s;  y[t + 1536] = v6  * s;  y[t + 1792] = v7  * s;
    y[t + 2048] = v8  * s;  y[t + 2304] = v9  * s;  y[t + 2560] = v10 * s;  y[t + 2816] = v11 * s;
    y[t + 3072] = v12 * s;  y[t + 3328] = v13 * s;  y[t + 3584] = v14 * s;  y[t + 3840] = v15 * s;
}

extern "C" void kernel_launch(void* const* d_in, const int* in_sizes, int n_in,
                              void* d_out, int out_size, void* d_ws, size_t ws_size,
                              hipStream_t stream) {
    const float* X = (const float*)d_in[0];   // (ROWS, 4096) fp32
    // d_in[1] (dense H) unused: FWHT computed directly.
    float* Y = (float*)d_out;
    const int rows = in_sizes[0] / N12;       // 8192
    hipLaunchKernelGGL(fwht4096_reg, dim3(rows), dim3(TPB), 0, stream, X, Y);
}